// Round 3
// baseline (289.596 us; speedup 1.0000x reference)
//
#include <hip/hip_runtime.h>

// Fused LSTM(H=128) + MLP head, 16x16x32 bf16 MFMA, fp32 state.
// 256 blocks x 512 threads (8 waves), 32 rows/block, wave owns 16 hcols.
// Weights in VGPRs (112/wave). 2 waves/SIMD target. 4 barriers/step.
// h panels parity-double-buffered; head folded into next step's gather
// via shuffle-reduced partials. Panel rows 40 shorts (80B): conflict-free.

#define T_STEPS 30
#define WARM_N  24
#define NT      512

typedef __attribute__((ext_vector_type(8))) short short8;   // 8 bf16
typedef __attribute__((ext_vector_type(4))) float floatx4;  // 16x16 C/D

struct FeatPtrs { const float* f[7]; };

__device__ __forceinline__ short f2bf(float f){
  unsigned u = __float_as_uint(f);
  return (short)((u + 0x7fffu + ((u >> 16) & 1u)) >> 16);
}
__device__ __forceinline__ float bf2f(short h){
  return __uint_as_float(((unsigned)(unsigned short)h) << 16);
}
__device__ __forceinline__ float sigm(float x){ return 1.0f/(1.0f + __expf(-x)); }
__device__ __forceinline__ float tanh_(float x){ return 1.0f - 2.0f/(__expf(2.0f*x) + 1.0f); }

// ---------------- weight pack ----------------
// 224 frags of 512 bf16. Frag (lane l, j): B[k=(l>>4)*8+j][n=colbase+(l&15)].
//  f 0..159   : z  [w 0..7][g 0..3][c 0..4]; c0 = x-chunk: k0..7=Wi, k8..15=Wi
//               (dup for hi+lo merged A), k16..31=0. c1..4: Wh k-chunks of 32.
//  f 160..191 : W1 [w][c 0..3];  f 192..223 : W2 [w][c 0..3].
__global__ void pack_weights(const float* __restrict__ Wi, const float* __restrict__ Wh,
                             const float* __restrict__ W1, const float* __restrict__ W2,
                             short* __restrict__ ws)
{
  int idx = blockIdx.x * 256 + threadIdx.x;
  if (idx >= 224 * 512) return;
  int f = idx >> 9, r = idx & 511;
  int l = r >> 3, j = r & 7;
  int k   = ((l >> 4) << 3) + j;          // 0..31
  int n16 = l & 15;
  float v;
  if (f < 160){
    int w = f / 20, rem = f % 20, g = rem / 5, c = rem % 5;
    int col = g * 128 + w * 16 + n16;
    if (c == 0) v = (k < 8) ? Wi[k * 512 + col]
                : (k < 16) ? Wi[(k - 8) * 512 + col] : 0.0f;
    else        v = Wh[((c - 1) * 32 + k) * 512 + col];
  } else if (f < 192){
    int f2 = f - 160, w = f2 >> 2, c = f2 & 3;
    v = W1[(c * 32 + k) * 128 + w * 16 + n16];
  } else {
    int f2 = f - 192, w = f2 >> 2, c = f2 & 3;
    v = W2[(c * 32 + k) * 128 + w * 16 + n16];
  }
  ws[idx] = f2bf(v);
}

// ---------------- main kernel ----------------
__global__ __launch_bounds__(NT, 2)
void lstm_mfma(FeatPtrs fp, const float* __restrict__ irr,
               const short* __restrict__ wsb,
               const float* __restrict__ bz, const float* __restrict__ b1,
               const float* __restrict__ b2, const float* __restrict__ Wout,
               const float* __restrict__ bout, float* __restrict__ out)
{
  // panels: rows of 40 shorts (32 data + 8 pad) = 80B, 16B-aligned reads
  __shared__ __align__(16) short xp[32 * 40];          // k0..7 x_hi, 8..15 x_lo, 16..31 zero
  __shared__ __align__(16) short hp[2][8][32 * 40];    // [parity][c: 0..3 hi, 4..7 lo]
  __shared__ __align__(16) short o1p[4][32 * 40];
  __shared__ float part[32][9];                        // per-wave head partials

  const int t    = threadIdx.x;
  const int l    = t & 63;
  const int w    = t >> 6;          // 0..7
  const int c15  = l & 15;
  const int quad = l >> 4;          // 0..3
  const int hcol = w * 16 + c15;
  const int r0   = blockIdx.x * 32;

  // weight fragments -> registers
  short8 Bz[4][5], B1f[4], B2f[4];
  {
    const short8* f8 = (const short8*)wsb;
#pragma unroll
    for (int g = 0; g < 4; ++g)
#pragma unroll
      for (int c = 0; c < 5; ++c)
        Bz[g][c] = f8[((w * 4 + g) * 5 + c) * 64 + l];
#pragma unroll
    for (int c = 0; c < 4; ++c) B1f[c] = f8[(160 + w * 4 + c) * 64 + l];
#pragma unroll
    for (int c = 0; c < 4; ++c) B2f[c] = f8[(192 + w * 4 + c) * 64 + l];
  }
  float bzv[4];
#pragma unroll
  for (int g = 0; g < 4; ++g) bzv[g] = bz[g * 128 + hcol];
  const float b1v = b1[hcol], b2v = b2[hcol];
  const float woutv = Wout[hcol];
  const float bout0 = bout[0];

  { // zero hp[0] (h0 = 0) and xp (pad k16..31 must be 0)
    int* p = (int*)&hp[0][0][0];
    for (int i = t; i < 8 * 640; i += NT) p[i] = 0;
    int* q = (int*)xp;
    for (int i = t; i < 640; i += NT) q[i] = 0;
  }
  float cst[2][4];
#pragma unroll
  for (int rt = 0; rt < 2; ++rt)
#pragma unroll
    for (int g = 0; g < 4; ++g) cst[rt][g] = 0.0f;

  const int aoff = quad * 8;                 // k-offset within row (shorts)
  const int wsub = (w & 1) * 16 + c15;       // k-in-chunk for activation writes
  const int wch  = w >> 1;                   // chunk for activation writes
  __syncthreads();

  for (int step = 0; step < T_STEPS; ++step){
    // ---- input gather + deferred head output ----
    if (t < 256){
      int r = t >> 3, j = t & 7;
      float v;
      if (j == 7){
        float p = 0.0f;
        if (step > 0){
          p = part[r][0] + part[r][1] + part[r][2] + part[r][3]
            + part[r][4] + part[r][5] + part[r][6] + part[r][7] + bout0;
          out[(r0 + r) * T_STEPS + (step - 1)] = p;
        }
        v = (step < WARM_N) ? irr[(r0 + r) * WARM_N + step] : p;
      } else {
        v = fp.f[j][(r0 + r) * T_STEPS + step];
      }
      short hi = f2bf(v);
      xp[r * 40 + j]     = hi;
      xp[r * 40 + 8 + j] = f2bf(v - bf2f(hi));
    }
    __syncthreads();                                   // B1

    const int rp = step & 1, wp = rp ^ 1;

    // ---- z = b + [x_hi,x_lo]@[Wi;Wi] + (h_hi+h_lo)@Wh ----
    floatx4 acc[2][4];
#pragma unroll
    for (int rt = 0; rt < 2; ++rt)
#pragma unroll
      for (int g = 0; g < 4; ++g)
#pragma unroll
        for (int q = 0; q < 4; ++q) acc[rt][g][q] = bzv[g];
#pragma unroll
    for (int rt = 0; rt < 2; ++rt){
      short8 ax = *(const short8*)&xp[(rt * 16 + c15) * 40 + aoff];
#pragma unroll
      for (int g = 0; g < 4; ++g)
        acc[rt][g] = __builtin_amdgcn_mfma_f32_16x16x32_bf16(ax, Bz[g][0], acc[rt][g], 0, 0, 0);
    }
#pragma unroll
    for (int c = 0; c < 4; ++c){
#pragma unroll
      for (int rt = 0; rt < 2; ++rt){
        short8 ah = *(const short8*)&hp[rp][c][(rt * 16 + c15) * 40 + aoff];
        short8 al = *(const short8*)&hp[rp][4 + c][(rt * 16 + c15) * 40 + aoff];
#pragma unroll
        for (int g = 0; g < 4; ++g){
          acc[rt][g] = __builtin_amdgcn_mfma_f32_16x16x32_bf16(ah, Bz[g][1 + c], acc[rt][g], 0, 0, 0);
          acc[rt][g] = __builtin_amdgcn_mfma_f32_16x16x32_bf16(al, Bz[g][1 + c], acc[rt][g], 0, 0, 0);
        }
      }
    }

    // ---- gates (fp32 in-lane), c update, h write (parity wp) ----
#pragma unroll
    for (int rt = 0; rt < 2; ++rt)
#pragma unroll
      for (int q = 0; q < 4; ++q){
        float zi = acc[rt][0][q], zf = acc[rt][1][q];
        float zg = acc[rt][2][q], zo = acc[rt][3][q];
        float c2 = sigm(zf) * cst[rt][q] + sigm(zi) * tanh_(zg);
        cst[rt][q] = c2;
        float h2 = sigm(zo) * tanh_(c2);
        int row = rt * 16 + quad * 4 + q;
        short hi = f2bf(h2);
        hp[wp][wch][row * 40 + wsub]     = hi;
        hp[wp][4 + wch][row * 40 + wsub] = f2bf(h2 - bf2f(hi));
      }
    __syncthreads();                                   // B2

    // ---- MLP1: o1 = relu(h@W1 + b1) ----
    floatx4 m1[2];
#pragma unroll
    for (int rt = 0; rt < 2; ++rt)
#pragma unroll
      for (int q = 0; q < 4; ++q) m1[rt][q] = b1v;
#pragma unroll
    for (int c = 0; c < 4; ++c)
#pragma unroll
      for (int rt = 0; rt < 2; ++rt){
        short8 ah = *(const short8*)&hp[wp][c][(rt * 16 + c15) * 40 + aoff];
        m1[rt] = __builtin_amdgcn_mfma_f32_16x16x32_bf16(ah, B1f[c], m1[rt], 0, 0, 0);
        short8 al = *(const short8*)&hp[wp][4 + c][(rt * 16 + c15) * 40 + aoff];
        m1[rt] = __builtin_amdgcn_mfma_f32_16x16x32_bf16(al, B1f[c], m1[rt], 0, 0, 0);
      }
#pragma unroll
    for (int rt = 0; rt < 2; ++rt)
#pragma unroll
      for (int q = 0; q < 4; ++q){
        int row = rt * 16 + quad * 4 + q;
        o1p[wch][row * 40 + wsub] = f2bf(fmaxf(m1[rt][q], 0.0f));
      }
    __syncthreads();                                   // B3

    // ---- MLP2 + head partials ----
    floatx4 m2[2];
#pragma unroll
    for (int rt = 0; rt < 2; ++rt)
#pragma unroll
      for (int q = 0; q < 4; ++q) m2[rt][q] = b2v;
#pragma unroll
    for (int c = 0; c < 4; ++c)
#pragma unroll
      for (int rt = 0; rt < 2; ++rt){
        short8 a = *(const short8*)&o1p[c][(rt * 16 + c15) * 40 + aoff];
        m2[rt] = __builtin_amdgcn_mfma_f32_16x16x32_bf16(a, B2f[c], m2[rt], 0, 0, 0);
      }
#pragma unroll
    for (int rt = 0; rt < 2; ++rt)
#pragma unroll
      for (int q = 0; q < 4; ++q){
        float s = fmaxf(m2[rt][q], 0.0f) * woutv;      // o2 * Wout[hcol]
        s += __shfl_down(s, 8, 16);
        s += __shfl_down(s, 4, 16);
        s += __shfl_down(s, 2, 16);
        s += __shfl_down(s, 1, 16);
        if (c15 == 0) part[rt * 16 + quad * 4 + q][w] = s;
      }
    __syncthreads();                                   // B4
  }

  // ---- final step's head output ----
  if (t < 32){
    float p = part[t][0] + part[t][1] + part[t][2] + part[t][3]
            + part[t][4] + part[t][5] + part[t][6] + part[t][7] + bout0;
    out[(r0 + t) * T_STEPS + (T_STEPS - 1)] = p;
  }
}

extern "C" void kernel_launch(void* const* d_in, const int* in_sizes, int n_in,
                              void* d_out, int out_size, void* d_ws, size_t ws_size,
                              hipStream_t stream)
{
  (void)in_sizes; (void)n_in; (void)out_size; (void)ws_size;
  FeatPtrs fp;
  for (int j = 0; j < 7; ++j) fp.f[j] = (const float*)d_in[8 + j];
  const float* irr  = (const float*)d_in[15];
  const float* Wi   = (const float*)d_in[16];
  const float* Wh   = (const float*)d_in[17];
  const float* bz   = (const float*)d_in[18];
  const float* W1   = (const float*)d_in[19];
  const float* b1   = (const float*)d_in[20];
  const float* W2   = (const float*)d_in[21];
  const float* b2   = (const float*)d_in[22];
  const float* Wout = (const float*)d_in[23];
  const float* bout = (const float*)d_in[24];

  short* ws = (short*)d_ws;                        // 224 KB used
  pack_weights<<<dim3(448), dim3(256), 0, stream>>>(Wi, Wh, W1, W2, ws);
  lstm_mfma<<<dim3(256), dim3(NT), 0, stream>>>(
      fp, irr, ws, bz, b1, b2, Wout, bout, (float*)d_out);
}